// Round 8
// baseline (111.306 us; speedup 1.0000x reference)
//
#include <hip/hip_runtime.h>
#include <cstdint>
#include <cstddef>

// ---------------------------------------------------------------------------
// CQAttention (B=16, Lc=1024, Lq=256, d=512)
//   S = (C*w4mlu)Q^T + C.w4C + (Q.w4Q)^T + bias, clipped to [-15,15]
//   S1 = masked_softmax(S, Qmask, axis=lq); S2 = masked_softmax(S, Cmask, lc)
//   A = S1 Q ; Bt = S1 (S2^T C)   [T^T = C^T S2 = Ctb . Eu^T, col-scale in T2]
//   out = [C, A, C*A, C*Bt]
// Fixed-shift softmax: S in [-15,15] => exp(x-8) safe, no max pass.
// 3 launches:
//   stage1: [S_fused] || [C->Ctb transpose + out seg0 copy] || [Q->QT^T]
//   stage2: [T2 64x64 (ids 0..511): Ctb.Eu^T -> T^T] || [AB-top: segs A, C*A]
//   stage3: AB-bottom: S1.(T^T)^T -> seg C*Bt
// ---------------------------------------------------------------------------

typedef __attribute__((ext_vector_type(8))) short short8;
typedef __attribute__((ext_vector_type(4))) short short4v;
typedef __attribute__((ext_vector_type(4))) float f32x4;
typedef __attribute__((ext_vector_type(8))) __bf16 bf16x8;

__device__ __forceinline__ short f2bf(float f) {
  unsigned u = __builtin_bit_cast(unsigned, f);
  u += 0x7fffu + ((u >> 16) & 1u);  // RNE
  return (short)(u >> 16);
}

__device__ __forceinline__ void gload16(const void* g, void* l) {
  __builtin_amdgcn_global_load_lds(
      (const __attribute__((address_space(1))) void*)g,
      (__attribute__((address_space(3))) void*)l, 16, 0, 0);
}

__device__ __forceinline__ f32x4 mfma16(short8 a, short8 b, f32x4 c) {
  return __builtin_amdgcn_mfma_f32_16x16x32_bf16(
      __builtin_bit_cast(bf16x8, a), __builtin_bit_cast(bf16x8, b), c, 0, 0, 0);
}

__device__ __forceinline__ short8 pack8(float4 x, float4 y) {
  short8 s;
  s[0] = f2bf(x.x); s[1] = f2bf(x.y); s[2] = f2bf(x.z); s[3] = f2bf(x.w);
  s[4] = f2bf(y.x); s[5] = f2bf(y.y); s[6] = f2bf(y.z); s[7] = f2bf(y.w);
  return s;
}
__device__ __forceinline__ float dot4(float4 a, float4 b) {
  return a.x * b.x + a.y * b.y + a.z * b.z + a.w * b.w;
}

// ---------------- bf16 NT GEMM cores ---------------------------------------
// A:[M,K] row-major, B:[N,K] row-major, D = A.B^T.

__device__ __forceinline__ void gemm_core(const short* __restrict__ A,
                                          const short* __restrict__ B, int K,
                                          int lda, int ldb, int m0, int n0,
                                          short* ldsA, short* ldsB,
                                          f32x4 (&acc)[4][4]) {
  const int tid = threadIdx.x;
  const int lane = tid & 63;
  const int wave = tid >> 6;
  const int wr = (wave >> 1) * 64, wc = (wave & 1) * 64;
  const int fr = lane & 15;
  const int fk = (lane >> 4) * 8;
  const int srow = tid >> 2;
  const int skoff = (tid & 3) * 8;

  const short* Ag = A + (size_t)(m0 + srow) * lda + skoff;
  const short* Ag2 = A + (size_t)(m0 + 64 + srow) * lda + skoff;
  const short* Bg = B + (size_t)(n0 + srow) * ldb + skoff;
  const short* Bg2 = B + (size_t)(n0 + 64 + srow) * ldb + skoff;
  short* la = ldsA + tid * 8;
  short* la2 = ldsA + 64 * 32 + tid * 8;
  short* lb = ldsB + tid * 8;
  short* lb2 = ldsB + 64 * 32 + tid * 8;

  for (int k0 = 0; k0 < K; k0 += 32) {
    gload16(Ag + k0, la);
    gload16(Ag2 + k0, la2);
    gload16(Bg + k0, lb);
    gload16(Bg2 + k0, lb2);
    __syncthreads();
    short8 af[4], bf[4];
#pragma unroll
    for (int m = 0; m < 4; ++m)
      af[m] = *(const short8*)(ldsA + (wr + m * 16 + fr) * 32 + fk);
#pragma unroll
    for (int n = 0; n < 4; ++n)
      bf[n] = *(const short8*)(ldsB + (wc + n * 16 + fr) * 32 + fk);
#pragma unroll
    for (int m = 0; m < 4; ++m)
#pragma unroll
      for (int n = 0; n < 4; ++n) acc[m][n] = mfma16(af[m], bf[n], acc[m][n]);
    __syncthreads();
  }
}

__device__ __forceinline__ void gemm_core64(const short* __restrict__ A,
                                            const short* __restrict__ B, int K,
                                            int lda, int ldb, int m0, int n0,
                                            short* ldsA, short* ldsB,
                                            f32x4 (&acc)[2][2]) {
  const int tid = threadIdx.x;
  const int lane = tid & 63;
  const int wave = tid >> 6;
  const int wr = (wave >> 1) * 32, wc = (wave & 1) * 32;
  const int fr = lane & 15;
  const int fk = (lane >> 4) * 8;
  const int srow = tid >> 2;
  const int skoff = (tid & 3) * 8;

  const short* Ag = A + (size_t)(m0 + srow) * lda + skoff;
  const short* Bg = B + (size_t)(n0 + srow) * ldb + skoff;
  short* la = ldsA + tid * 8;
  short* lb = ldsB + tid * 8;

  for (int k0 = 0; k0 < K; k0 += 32) {
    gload16(Ag + k0, la);
    gload16(Bg + k0, lb);
    __syncthreads();
    short8 af[2], bf[2];
#pragma unroll
    for (int m = 0; m < 2; ++m)
      af[m] = *(const short8*)(ldsA + (wr + m * 16 + fr) * 32 + fk);
#pragma unroll
    for (int n = 0; n < 2; ++n)
      bf[n] = *(const short8*)(ldsB + (wc + n * 16 + fr) * 32 + fk);
#pragma unroll
    for (int m = 0; m < 2; ++m)
#pragma unroll
      for (int n = 0; n < 2; ++n) acc[m][n] = mfma16(af[m], bf[n], acc[m][n]);
    __syncthreads();
  }
}

// ---------------- 64x64 transpose tiles (fp32 in -> bf16 out) --------------

// C tile: also copies the fp32 values to out segment 0 (nontemporal).
__device__ __forceinline__ void prep_tile64_c(const float* __restrict__ ip,
                                              short* __restrict__ op,
                                              float* __restrict__ outp,
                                              int r0, int c0, short* tile) {
  const int tx = threadIdx.x & 15, ty = threadIdx.x >> 4;  // 16x16
#pragma unroll
  for (int i = 0; i < 64; i += 16) {
    float4 v = *(const float4*)(ip + (size_t)(r0 + ty + i) * 512 + c0 + tx * 4);
    f32x4 vv = {v.x, v.y, v.z, v.w};
    __builtin_nontemporal_store(
        vv, (f32x4*)(outp + (size_t)(r0 + ty + i) * 2048 + c0 + tx * 4));
    short* t = tile + (ty + i) * 66 + tx * 4;
    t[0] = f2bf(v.x); t[1] = f2bf(v.y); t[2] = f2bf(v.z); t[3] = f2bf(v.w);
  }
  __syncthreads();
#pragma unroll
  for (int i = 0; i < 64; i += 16) {
    const int orow = ty + i, ocol = tx * 4;
    short4v o;
#pragma unroll
    for (int j = 0; j < 4; ++j) o[j] = tile[(ocol + j) * 66 + orow];
    *(short4v*)(op + (size_t)(c0 + orow) * 1024 + r0 + ocol) = o;
  }
}

__device__ __forceinline__ void prep_tile64_q(const float* __restrict__ ip,
                                              short* __restrict__ op,
                                              int r0, int c0, short* tile) {
  const int tx = threadIdx.x & 15, ty = threadIdx.x >> 4;
#pragma unroll
  for (int i = 0; i < 64; i += 16) {
    float4 v = *(const float4*)(ip + (size_t)(r0 + ty + i) * 512 + c0 + tx * 4);
    short* t = tile + (ty + i) * 66 + tx * 4;
    t[0] = f2bf(v.x); t[1] = f2bf(v.y); t[2] = f2bf(v.z); t[3] = f2bf(v.w);
  }
  __syncthreads();
#pragma unroll
  for (int i = 0; i < 64; i += 16) {
    const int orow = ty + i, ocol = tx * 4;
    short4v o;
#pragma unroll
    for (int j = 0; j < 4; ++j) o[j] = tile[(ocol + j) * 66 + orow];
    *(short4v*)(op + (size_t)(c0 + orow) * 256 + r0 + ocol) = o;
  }
}

// ---------------- fused S-GEMM + both softmax exponentials -----------------
// tile 64(lc) x 256(lq full), 4 waves along N, reg-staged from fp32.

__device__ __forceinline__ void s_fused_body(
    const float* __restrict__ C, const float* __restrict__ Q,
    const int* __restrict__ Qmask, const int* __restrict__ Cmask,
    const float* __restrict__ w4C, const float* __restrict__ w4Q,
    const float* __restrict__ w4mlu, const float* __restrict__ bias,
    short* __restrict__ S1, short* __restrict__ Eu,
    float* __restrict__ partial, int b, int mblk, char* sm) {
  short* ldsA = (short*)sm;                   // [64][32]
  short* ldsB = (short*)(sm + 64 * 32 * 2);   // [256][32]
  short* eT = (short*)sm;                     // phase2 alias: [256][72]
  float* sub0_l = (float*)(sm + 36864);       // [64]
  float* sub1_l = (float*)(sm + 37120);       // [256]
  float(*redS)[64] = (float(*)[64])(sm + 38144);  // [4][64]

  const int m0 = mblk * 64;
  const int tid = threadIdx.x;
  const int lane = tid & 63, wave = tid >> 6;

  const float* Cb = C + ((size_t)b * 1024 + m0) * 512;
  const float* Qb = Q + (size_t)b * 256 * 512;

  const int srow = tid >> 2;      // 0..63
  const int skk = (tid & 3) * 8;  // 0,8,16,24

  f32x4 acc[4][4];
  {
    f32x4 z = {0.f, 0.f, 0.f, 0.f};
#pragma unroll
    for (int m = 0; m < 4; ++m)
#pragma unroll
      for (int n = 0; n < 4; ++n) acc[m][n] = z;
  }
  float dotA = 0.f;
  float dotB[4] = {0.f, 0.f, 0.f, 0.f};

  const int fr = lane & 15, fk = (lane >> 4) * 8;

  for (int k0 = 0; k0 < 512; k0 += 32) {
    float4 a0 = *(const float4*)(Cb + (size_t)srow * 512 + k0 + skk);
    float4 a1 = *(const float4*)(Cb + (size_t)srow * 512 + k0 + skk + 4);
    float4 q0[4], q1[4];
#pragma unroll
    for (int r4 = 0; r4 < 4; ++r4) {
      const float* qp = Qb + (size_t)(srow + 64 * r4) * 512 + k0 + skk;
      q0[r4] = *(const float4*)qp;
      q1[r4] = *(const float4*)(qp + 4);
    }
    float4 wm0 = *(const float4*)(w4mlu + k0 + skk);
    float4 wm1 = *(const float4*)(w4mlu + k0 + skk + 4);
    float4 wc0 = *(const float4*)(w4C + k0 + skk);
    float4 wc1 = *(const float4*)(w4C + k0 + skk + 4);
    float4 wq0 = *(const float4*)(w4Q + k0 + skk);
    float4 wq1 = *(const float4*)(w4Q + k0 + skk + 4);

    dotA += dot4(a0, wc0) + dot4(a1, wc1);
#pragma unroll
    for (int r4 = 0; r4 < 4; ++r4)
      dotB[r4] += dot4(q0[r4], wq0) + dot4(q1[r4], wq1);

    float4 am0, am1;
    am0.x = a0.x * wm0.x; am0.y = a0.y * wm0.y;
    am0.z = a0.z * wm0.z; am0.w = a0.w * wm0.w;
    am1.x = a1.x * wm1.x; am1.y = a1.y * wm1.y;
    am1.z = a1.z * wm1.z; am1.w = a1.w * wm1.w;
    short8 as = pack8(am0, am1);
    short8 bs[4];
#pragma unroll
    for (int r4 = 0; r4 < 4; ++r4) bs[r4] = pack8(q0[r4], q1[r4]);

    __syncthreads();
    *(short8*)(ldsA + srow * 32 + skk) = as;
#pragma unroll
    for (int r4 = 0; r4 < 4; ++r4)
      *(short8*)(ldsB + (srow + 64 * r4) * 32 + skk) = bs[r4];
    __syncthreads();

    short8 af[4], bfv[4];
#pragma unroll
    for (int m = 0; m < 4; ++m)
      af[m] = *(const short8*)(ldsA + (m * 16 + fr) * 32 + fk);
#pragma unroll
    for (int n = 0; n < 4; ++n)
      bfv[n] = *(const short8*)(ldsB + (wave * 64 + n * 16 + fr) * 32 + fk);
#pragma unroll
    for (int m = 0; m < 4; ++m)
#pragma unroll
      for (int n = 0; n < 4; ++n) acc[m][n] = mfma16(af[m], bfv[n], acc[m][n]);
  }

  // ---- sub0 / sub1 reductions (4 k-partials per row, lanes tid&3) ----
  dotA += __shfl_xor(dotA, 1, 64);
  dotA += __shfl_xor(dotA, 2, 64);
#pragma unroll
  for (int r4 = 0; r4 < 4; ++r4) {
    dotB[r4] += __shfl_xor(dotB[r4], 1, 64);
    dotB[r4] += __shfl_xor(dotB[r4], 2, 64);
  }
  if ((tid & 3) == 0) {
    sub0_l[srow] = dotA;
#pragma unroll
    for (int r4 = 0; r4 < 4; ++r4) sub1_l[srow + 64 * r4] = dotB[r4];
  }
  __syncthreads();  // also drains LDS fragment reads -> eT alias safe

  // ---- v = clip(acc + subs + bias) ----
  const float bv = bias[0];
  const int cc = lane & 15, cr = (lane >> 4) * 4;
  float qmv[4];
#pragma unroll
  for (int n = 0; n < 4; ++n)
    qmv[n] = (float)Qmask[b * 256 + wave * 64 + n * 16 + cc];
  float cmv[4][4];
#pragma unroll
  for (int m = 0; m < 4; ++m)
#pragma unroll
    for (int i = 0; i < 4; ++i)
      cmv[m][i] = (float)Cmask[b * 1024 + m0 + m * 16 + cr + i];

#pragma unroll
  for (int m = 0; m < 4; ++m)
#pragma unroll
    for (int n = 0; n < 4; ++n)
#pragma unroll
      for (int i = 0; i < 4; ++i) {
        float v = acc[m][n][i] + sub0_l[m * 16 + cr + i] +
                  sub1_l[wave * 64 + n * 16 + cc] + bv;
        acc[m][n][i] = fminf(15.f, fmaxf(-15.f, v));
      }

  // ---- column exp into LDS transpose buffer + partial col sums ----
  float ps[4] = {0.f, 0.f, 0.f, 0.f};
#pragma unroll
  for (int m = 0; m < 4; ++m)
#pragma unroll
    for (int n = 0; n < 4; ++n) {
      short4v o;
#pragma unroll
      for (int i = 0; i < 4; ++i) {
        float cm = cmv[m][i];
        float ec = cm * __expf(acc[m][n][i] * cm - 8.f);
        ps[n] += ec;
        o[i] = f2bf(ec);
      }
      *(short4v*)(eT + (wave * 64 + n * 16 + cc) * 72 + m * 16 + cr) = o;
    }
#pragma unroll
  for (int n = 0; n < 4; ++n) {
    ps[n] += __shfl_xor(ps[n], 16, 64);
    ps[n] += __shfl_xor(ps[n], 32, 64);
  }
  if (lane < 16) {
#pragma unroll
    for (int n = 0; n < 4; ++n)
      partial[((size_t)b * 16 + mblk) * 256 + wave * 64 + n * 16 + cc] = ps[n];
  }
  __syncthreads();  // eT complete

  // ---- write Eu [lq][lc] (transposed) ----
  short* Eub = Eu + (size_t)b * 262144 + m0;
#pragma unroll
  for (int it = 0; it < 8; ++it) {
    int q = it * 32 + wave * 8 + (lane >> 3);
    int k = lane & 7;
    short8 v = *(const short8*)(eT + q * 72 + k * 8);
    *(short8*)(Eub + (size_t)q * 1024 + k * 8) = v;
  }

  // ---- row exp + row sum -> S1 = eq/(sum+1e-6) ----
  float rs[4][4];
#pragma unroll
  for (int m = 0; m < 4; ++m)
#pragma unroll
    for (int i = 0; i < 4; ++i) {
      rs[m][i] = 0.f;
#pragma unroll
      for (int n = 0; n < 4; ++n) {
        float eq = qmv[n] * __expf(acc[m][n][i] * qmv[n] - 8.f);
        acc[m][n][i] = eq;
        rs[m][i] += eq;
      }
    }
#pragma unroll
  for (int m = 0; m < 4; ++m)
#pragma unroll
    for (int i = 0; i < 4; ++i) {
      rs[m][i] += __shfl_xor(rs[m][i], 1, 64);
      rs[m][i] += __shfl_xor(rs[m][i], 2, 64);
      rs[m][i] += __shfl_xor(rs[m][i], 4, 64);
      rs[m][i] += __shfl_xor(rs[m][i], 8, 64);
    }
  if (cc == 0) {
#pragma unroll
    for (int m = 0; m < 4; ++m)
#pragma unroll
      for (int i = 0; i < 4; ++i) redS[wave][m * 16 + cr + i] = rs[m][i];
  }
  __syncthreads();

  short* S1b = S1 + (size_t)b * 262144 + (size_t)m0 * 256;
#pragma unroll
  for (int m = 0; m < 4; ++m)
#pragma unroll
    for (int i = 0; i < 4; ++i) {
      int r = m * 16 + cr + i;
      float sum = redS[0][r] + redS[1][r] + redS[2][r] + redS[3][r];
      float inv = 1.f / (sum + 1e-6f);
#pragma unroll
      for (int n = 0; n < 4; ++n)
        S1b[(size_t)r * 256 + wave * 64 + n * 16 + cc] =
            f2bf(acc[m][n][i] * inv);
    }
}

// ---------------- stage1: S_fused || C-transpose(+seg0) || Q-transpose -----
// flat grid: [0,256) S_fused; [256,2304) prepC; [2304,2816) prepQ

__global__ __launch_bounds__(256) void stage1(
    const float* __restrict__ C, const float* __restrict__ Q,
    const int* __restrict__ Qmask, const int* __restrict__ Cmask,
    const float* __restrict__ w4C, const float* __restrict__ w4Q,
    const float* __restrict__ w4mlu, const float* __restrict__ bias,
    short* __restrict__ S1, short* __restrict__ Eu,
    float* __restrict__ partial, short* __restrict__ Ctb,
    short* __restrict__ QT, float* __restrict__ out) {
  __shared__ __attribute__((aligned(16))) char sm[39168];
  const int id = blockIdx.x;
  if (id < 256) {
    s_fused_body(C, Q, Qmask, Cmask, w4C, w4Q, w4mlu, bias, S1, Eu, partial,
                 id >> 4, id & 15, sm);
  } else if (id < 2304) {
    const int p = id - 256, b = p >> 7, t = p & 127;
    prep_tile64_c(C + (size_t)b * 1024 * 512, Ctb + (size_t)b * 512 * 1024,
                  out + (size_t)b * 1024 * 2048, (t >> 3) * 64, (t & 7) * 64,
                  (short*)sm);
  } else {
    const int p = id - 2304, b = p >> 5, t = p & 31;
    prep_tile64_q(Q + (size_t)b * 256 * 512, QT + (size_t)b * 1024 * 256,
                  (t >> 3) * 64, (t & 7) * 64, (short*)sm);
  }
}

// ---------------- stage2: T2 (first) || AB-top ------------------------------
// flat grid: [0,512) T2 (64x64); [512,1024) AB-top (segs A, C*A).

__global__ __launch_bounds__(256) void stage2(
    const short* __restrict__ Ctb, const short* __restrict__ Eu,
    const float* __restrict__ partial, short* __restrict__ QT,
    const short* __restrict__ S1, const float* __restrict__ C,
    float* __restrict__ out) {
  __shared__ __attribute__((aligned(16))) char sm[16384];
  short* ldsA = (short*)sm;
  short* ldsB = (short*)(sm + 8192);
  const int id = blockIdx.x;
  const int lane = threadIdx.x & 63, wave = threadIdx.x >> 6;
  const int cr = (lane >> 4) * 4, cc = lane & 15;

  if (id < 512) {
    // ---- T2: T^T = Ctb . Eu^T, col-scaled; M=512 N=256 K=1024, 64x64 ----
    const int b = id >> 5, r = id & 31;
    const int m0 = (r >> 2) * 64, n0 = (r & 3) * 64;
    const int wr = (wave >> 1) * 32, wc = (wave & 1) * 32;
    f32x4 acc[2][2];
    {
      f32x4 z = {0.f, 0.f, 0.f, 0.f};
#pragma unroll
      for (int m = 0; m < 2; ++m)
#pragma unroll
        for (int n = 0; n < 2; ++n) acc[m][n] = z;
    }
    gemm_core64(Ctb + (size_t)b * 512 * 1024, Eu + (size_t)b * 256 * 1024,
                1024, 1024, 1024, m0, n0, ldsA, ldsB, acc);
    const float* pb = partial + (size_t)b * 16 * 256;
    float invv[2];
#pragma unroll
    for (int n = 0; n < 2; ++n) {
      int c = n0 + wc + n * 16 + cc;
      float s = 0.f;
#pragma unroll
      for (int k = 0; k < 16; ++k) s += pb[k * 256 + c];
      invv[n] = 1.f / (s + 1e-6f);
    }
    short* Tp = QT + (size_t)b * 1024 * 256 + 512 * 256;
#pragma unroll
    for (int m = 0; m < 2; ++m)
#pragma unroll
      for (int n = 0; n < 2; ++n)
#pragma unroll
        for (int i = 0; i < 4; ++i) {
          int rr = m0 + wr + m * 16 + cr + i;
          int c = n0 + wc + n * 16 + cc;
          Tp[(size_t)rr * 256 + c] = f2bf(acc[m][n][i] * invv[n]);
        }
  } else {
    // ---- AB-top: out segs {A, C*A}, M=1024 N=512(Q^T rows) K=256 ----
    const int t = id - 512;
    const int b = t >> 5, r = t & 31;
    const int m0 = (r >> 2) * 128, n0 = (r & 3) * 128;
    const int wr = (wave >> 1) * 64, wc = (wave & 1) * 64;
    f32x4 acc[4][4];
    {
      f32x4 z = {0.f, 0.f, 0.f, 0.f};
#pragma unroll
      for (int m = 0; m < 4; ++m)
#pragma unroll
        for (int n = 0; n < 4; ++n) acc[m][n] = z;
    }
    gemm_core(S1 + (size_t)b * 1024 * 256, QT + (size_t)b * 1024 * 256, 256,
              256, 256, m0, n0, ldsA, ldsB, acc);
#pragma unroll
    for (int m = 0; m < 4; ++m)
#pragma unroll
      for (int n = 0; n < 4; ++n)
#pragma unroll
        for (int i = 0; i < 4; ++i) {
          int rr = m0 + wr + m * 16 + cr + i;
          int c = n0 + wc + n * 16 + cc;
          float a = acc[m][n][i];
          float cv = C[((size_t)b * 1024 + rr) * 512 + c];
          size_t base = ((size_t)b * 1024 + rr) * 2048;
          __builtin_nontemporal_store(a, &out[base + 512 + c]);
          __builtin_nontemporal_store(cv * a, &out[base + 1024 + c]);
        }
  }
}

// ---------------- stage3: AB-bottom (C*Bt segment) -------------------------
// M=1024, N=512 (QT rows 512..1023 = T^T), K=256. grid (8,4,16).

__global__ __launch_bounds__(256) void gemm_ABbot(const short* __restrict__ S1,
                                                  const short* __restrict__ QT,
                                                  const float* __restrict__ C,
                                                  float* __restrict__ out) {
  __shared__ __attribute__((aligned(16))) short ldsA[128 * 32];
  __shared__ __attribute__((aligned(16))) short ldsB[128 * 32];
  const int b = blockIdx.z;
  const int m0 = blockIdx.x * 128, n0 = 512 + blockIdx.y * 128;
  f32x4 acc[4][4];
  {
    f32x4 z = {0.f, 0.f, 0.f, 0.f};
#pragma unroll
    for (int m = 0; m < 4; ++m)
#pragma unroll
      for (int n = 0; n < 4; ++n) acc[m][n] = z;
  }
  const int lane = threadIdx.x & 63, wave = threadIdx.x >> 6;
  const int wr = (wave >> 1) * 64, wc = (wave & 1) * 64;
  const int cr = (lane >> 4) * 4, cc = lane & 15;
  gemm_core(S1 + (size_t)b * 1024 * 256, QT + (size_t)b * 1024 * 256, 256, 256,
            256, m0, n0, ldsA, ldsB, acc);
#pragma unroll
  for (int m = 0; m < 4; ++m)
#pragma unroll
    for (int n = 0; n < 4; ++n)
#pragma unroll
      for (int i = 0; i < 4; ++i) {
        int rr = m0 + wr + m * 16 + cr + i;
        int cq = (n0 - 512) + wc + n * 16 + cc;
        float cv = C[((size_t)b * 1024 + rr) * 512 + cq];
        size_t base = ((size_t)b * 1024 + rr) * 2048;
        __builtin_nontemporal_store(cv * acc[m][n][i], &out[base + 1536 + cq]);
      }
}

// ---------------------------------------------------------------------------

extern "C" void kernel_launch(void* const* d_in, const int* in_sizes, int n_in,
                              void* d_out, int out_size, void* d_ws,
                              size_t ws_size, hipStream_t stream) {
  const float* C = (const float*)d_in[0];
  const float* Q = (const float*)d_in[1];
  const int* Cmask = (const int*)d_in[2];
  const int* Qmask = (const int*)d_in[3];
  const float* w4C = (const float*)d_in[4];
  const float* w4Q = (const float*)d_in[5];
  const float* w4mlu = (const float*)d_in[6];
  const float* bias = (const float*)d_in[7];
  float* out = (float*)d_out;

  size_t off = 0;
  auto alloc = [&](size_t n) {
    void* p = (char*)d_ws + off;
    off += (n + 255) & ~(size_t)255;
    return p;
  };
  short* Ctb = (short*)alloc((size_t)16 * 512 * 1024 * 2);    // [b][d][lc]
  short* QT = (short*)alloc((size_t)16 * 1024 * 256 * 2);     // [b][Q^T;T^T][lq]
  short* S1 = (short*)alloc((size_t)16 * 1024 * 256 * 2);     // [b][lc][lq]
  short* Eu = (short*)alloc((size_t)16 * 256 * 1024 * 2);     // [b][lq][lc]
  float* partial = (float*)alloc((size_t)16 * 16 * 256 * 4);  // [b][mblk][lq]

  stage1<<<dim3(2816), dim3(256), 0, stream>>>(C, Q, Qmask, Cmask, w4C, w4Q,
                                               w4mlu, bias, S1, Eu, partial,
                                               Ctb, QT, out);
  stage2<<<dim3(1024), dim3(256), 0, stream>>>(Ctb, Eu, partial, QT, S1, C,
                                               out);
  gemm_ABbot<<<dim3(8, 4, 16), dim3(256), 0, stream>>>(S1, QT, C, out);
}

// Round 9
// 105.458 us; speedup vs baseline: 1.0555x; 1.0555x over previous
//
#include <hip/hip_runtime.h>
#include <cstdint>
#include <cstddef>

// ---------------------------------------------------------------------------
// CQAttention (B=16, Lc=1024, Lq=256, d=512)
//   S = (C*w4mlu)Q^T + C.w4C + (Q.w4Q)^T + bias, clipped to [-15,15]
//   S1 = masked_softmax(S, Qmask, axis=lq); S2 = masked_softmax(S, Cmask, lc)
//   A = S1 Q ; Bt = S1 (S2^T C)   [T^T = C^T S2 = Ctb . Eu^T, col-scale in T2]
//   out = [C, A, C*A, C*Bt]
// Fixed-shift softmax: S in [-15,15] => exp(x-8) safe, no max pass.
// 3 launches (R5 structure — measured best 105.6us):
//   stage1: [S_fused GEMM+softmaxes] || [C->Ctb 64x64 transpose] || [Q->QT^T]
//   stage2: [AB-top: S1.QT^T -> out segs C,A,C*A] || [T2 64x64: Ctb.Eu^T -> T^T]
//   stage3: AB-bottom: S1.(T^T)^T -> out seg C*Bt
// ---------------------------------------------------------------------------

typedef __attribute__((ext_vector_type(8))) short short8;
typedef __attribute__((ext_vector_type(4))) short short4v;
typedef __attribute__((ext_vector_type(4))) float f32x4;
typedef __attribute__((ext_vector_type(8))) __bf16 bf16x8;

__device__ __forceinline__ short f2bf(float f) {
  unsigned u = __builtin_bit_cast(unsigned, f);
  u += 0x7fffu + ((u >> 16) & 1u);  // RNE
  return (short)(u >> 16);
}

__device__ __forceinline__ void gload16(const void* g, void* l) {
  __builtin_amdgcn_global_load_lds(
      (const __attribute__((address_space(1))) void*)g,
      (__attribute__((address_space(3))) void*)l, 16, 0, 0);
}

__device__ __forceinline__ f32x4 mfma16(short8 a, short8 b, f32x4 c) {
  return __builtin_amdgcn_mfma_f32_16x16x32_bf16(
      __builtin_bit_cast(bf16x8, a), __builtin_bit_cast(bf16x8, b), c, 0, 0, 0);
}

__device__ __forceinline__ short8 pack8(float4 x, float4 y) {
  short8 s;
  s[0] = f2bf(x.x); s[1] = f2bf(x.y); s[2] = f2bf(x.z); s[3] = f2bf(x.w);
  s[4] = f2bf(y.x); s[5] = f2bf(y.y); s[6] = f2bf(y.z); s[7] = f2bf(y.w);
  return s;
}
__device__ __forceinline__ float dot4(float4 a, float4 b) {
  return a.x * b.x + a.y * b.y + a.z * b.z + a.w * b.w;
}

// ---------------- bf16 NT GEMM cores ---------------------------------------
// A:[M,K] row-major, B:[N,K] row-major, D = A.B^T.

__device__ __forceinline__ void gemm_core(const short* __restrict__ A,
                                          const short* __restrict__ B, int K,
                                          int lda, int ldb, int m0, int n0,
                                          short* ldsA, short* ldsB,
                                          f32x4 (&acc)[4][4]) {
  const int tid = threadIdx.x;
  const int lane = tid & 63;
  const int wave = tid >> 6;
  const int wr = (wave >> 1) * 64, wc = (wave & 1) * 64;
  const int fr = lane & 15;
  const int fk = (lane >> 4) * 8;
  const int srow = tid >> 2;
  const int skoff = (tid & 3) * 8;

  const short* Ag = A + (size_t)(m0 + srow) * lda + skoff;
  const short* Ag2 = A + (size_t)(m0 + 64 + srow) * lda + skoff;
  const short* Bg = B + (size_t)(n0 + srow) * ldb + skoff;
  const short* Bg2 = B + (size_t)(n0 + 64 + srow) * ldb + skoff;
  short* la = ldsA + tid * 8;
  short* la2 = ldsA + 64 * 32 + tid * 8;
  short* lb = ldsB + tid * 8;
  short* lb2 = ldsB + 64 * 32 + tid * 8;

  for (int k0 = 0; k0 < K; k0 += 32) {
    gload16(Ag + k0, la);
    gload16(Ag2 + k0, la2);
    gload16(Bg + k0, lb);
    gload16(Bg2 + k0, lb2);
    __syncthreads();
    short8 af[4], bf[4];
#pragma unroll
    for (int m = 0; m < 4; ++m)
      af[m] = *(const short8*)(ldsA + (wr + m * 16 + fr) * 32 + fk);
#pragma unroll
    for (int n = 0; n < 4; ++n)
      bf[n] = *(const short8*)(ldsB + (wc + n * 16 + fr) * 32 + fk);
#pragma unroll
    for (int m = 0; m < 4; ++m)
#pragma unroll
      for (int n = 0; n < 4; ++n) acc[m][n] = mfma16(af[m], bf[n], acc[m][n]);
    __syncthreads();
  }
}

__device__ __forceinline__ void gemm_core64(const short* __restrict__ A,
                                            const short* __restrict__ B, int K,
                                            int lda, int ldb, int m0, int n0,
                                            short* ldsA, short* ldsB,
                                            f32x4 (&acc)[2][2]) {
  const int tid = threadIdx.x;
  const int lane = tid & 63;
  const int wave = tid >> 6;
  const int wr = (wave >> 1) * 32, wc = (wave & 1) * 32;
  const int fr = lane & 15;
  const int fk = (lane >> 4) * 8;
  const int srow = tid >> 2;
  const int skoff = (tid & 3) * 8;

  const short* Ag = A + (size_t)(m0 + srow) * lda + skoff;
  const short* Bg = B + (size_t)(n0 + srow) * ldb + skoff;
  short* la = ldsA + tid * 8;
  short* lb = ldsB + tid * 8;

  for (int k0 = 0; k0 < K; k0 += 32) {
    gload16(Ag + k0, la);
    gload16(Bg + k0, lb);
    __syncthreads();
    short8 af[2], bf[2];
#pragma unroll
    for (int m = 0; m < 2; ++m)
      af[m] = *(const short8*)(ldsA + (wr + m * 16 + fr) * 32 + fk);
#pragma unroll
    for (int n = 0; n < 2; ++n)
      bf[n] = *(const short8*)(ldsB + (wc + n * 16 + fr) * 32 + fk);
#pragma unroll
    for (int m = 0; m < 2; ++m)
#pragma unroll
      for (int n = 0; n < 2; ++n) acc[m][n] = mfma16(af[m], bf[n], acc[m][n]);
    __syncthreads();
  }
}

// ---------------- 64x64 transpose tile (fp32 in -> bf16 out) ---------------

__device__ __forceinline__ void prep_tile64(const float* __restrict__ ip,
                                            short* __restrict__ op, int outld,
                                            int r0, int c0, short* tile) {
  const int tx = threadIdx.x & 15, ty = threadIdx.x >> 4;  // 16x16
#pragma unroll
  for (int i = 0; i < 64; i += 16) {
    float4 v = *(const float4*)(ip + (size_t)(r0 + ty + i) * 512 + c0 + tx * 4);
    short* t = tile + (ty + i) * 66 + tx * 4;
    t[0] = f2bf(v.x); t[1] = f2bf(v.y); t[2] = f2bf(v.z); t[3] = f2bf(v.w);
  }
  __syncthreads();
#pragma unroll
  for (int i = 0; i < 64; i += 16) {
    const int orow = ty + i, ocol = tx * 4;
    short4v o;
#pragma unroll
    for (int j = 0; j < 4; ++j) o[j] = tile[(ocol + j) * 66 + orow];
    *(short4v*)(op + (size_t)(c0 + orow) * outld + r0 + ocol) = o;
  }
}

// ---------------- fused S-GEMM + both softmax exponentials -----------------
// tile 64(lc) x 256(lq full), 4 waves along N, reg-staged from fp32.

__device__ __forceinline__ void s_fused_body(
    const float* __restrict__ C, const float* __restrict__ Q,
    const int* __restrict__ Qmask, const int* __restrict__ Cmask,
    const float* __restrict__ w4C, const float* __restrict__ w4Q,
    const float* __restrict__ w4mlu, const float* __restrict__ bias,
    short* __restrict__ S1, short* __restrict__ Eu,
    float* __restrict__ partial, int b, int mblk, char* sm) {
  short* ldsA = (short*)sm;                   // [64][32]
  short* ldsB = (short*)(sm + 64 * 32 * 2);   // [256][32]
  short* eT = (short*)sm;                     // phase2 alias: [256][72]
  float* sub0_l = (float*)(sm + 36864);       // [64]
  float* sub1_l = (float*)(sm + 37120);       // [256]
  float(*redS)[64] = (float(*)[64])(sm + 38144);  // [4][64]

  const int m0 = mblk * 64;
  const int tid = threadIdx.x;
  const int lane = tid & 63, wave = tid >> 6;

  const float* Cb = C + ((size_t)b * 1024 + m0) * 512;
  const float* Qb = Q + (size_t)b * 256 * 512;

  const int srow = tid >> 2;      // 0..63
  const int skk = (tid & 3) * 8;  // 0,8,16,24

  f32x4 acc[4][4];
  {
    f32x4 z = {0.f, 0.f, 0.f, 0.f};
#pragma unroll
    for (int m = 0; m < 4; ++m)
#pragma unroll
      for (int n = 0; n < 4; ++n) acc[m][n] = z;
  }
  float dotA = 0.f;
  float dotB[4] = {0.f, 0.f, 0.f, 0.f};

  const int fr = lane & 15, fk = (lane >> 4) * 8;

  for (int k0 = 0; k0 < 512; k0 += 32) {
    float4 a0 = *(const float4*)(Cb + (size_t)srow * 512 + k0 + skk);
    float4 a1 = *(const float4*)(Cb + (size_t)srow * 512 + k0 + skk + 4);
    float4 q0[4], q1[4];
#pragma unroll
    for (int r4 = 0; r4 < 4; ++r4) {
      const float* qp = Qb + (size_t)(srow + 64 * r4) * 512 + k0 + skk;
      q0[r4] = *(const float4*)qp;
      q1[r4] = *(const float4*)(qp + 4);
    }
    float4 wm0 = *(const float4*)(w4mlu + k0 + skk);
    float4 wm1 = *(const float4*)(w4mlu + k0 + skk + 4);
    float4 wc0 = *(const float4*)(w4C + k0 + skk);
    float4 wc1 = *(const float4*)(w4C + k0 + skk + 4);
    float4 wq0 = *(const float4*)(w4Q + k0 + skk);
    float4 wq1 = *(const float4*)(w4Q + k0 + skk + 4);

    dotA += dot4(a0, wc0) + dot4(a1, wc1);
#pragma unroll
    for (int r4 = 0; r4 < 4; ++r4)
      dotB[r4] += dot4(q0[r4], wq0) + dot4(q1[r4], wq1);

    float4 am0, am1;
    am0.x = a0.x * wm0.x; am0.y = a0.y * wm0.y;
    am0.z = a0.z * wm0.z; am0.w = a0.w * wm0.w;
    am1.x = a1.x * wm1.x; am1.y = a1.y * wm1.y;
    am1.z = a1.z * wm1.z; am1.w = a1.w * wm1.w;
    short8 as = pack8(am0, am1);
    short8 bs[4];
#pragma unroll
    for (int r4 = 0; r4 < 4; ++r4) bs[r4] = pack8(q0[r4], q1[r4]);

    __syncthreads();
    *(short8*)(ldsA + srow * 32 + skk) = as;
#pragma unroll
    for (int r4 = 0; r4 < 4; ++r4)
      *(short8*)(ldsB + (srow + 64 * r4) * 32 + skk) = bs[r4];
    __syncthreads();

    short8 af[4], bfv[4];
#pragma unroll
    for (int m = 0; m < 4; ++m)
      af[m] = *(const short8*)(ldsA + (m * 16 + fr) * 32 + fk);
#pragma unroll
    for (int n = 0; n < 4; ++n)
      bfv[n] = *(const short8*)(ldsB + (wave * 64 + n * 16 + fr) * 32 + fk);
#pragma unroll
    for (int m = 0; m < 4; ++m)
#pragma unroll
      for (int n = 0; n < 4; ++n) acc[m][n] = mfma16(af[m], bfv[n], acc[m][n]);
  }

  // ---- sub0 / sub1 reductions (4 k-partials per row, lanes tid&3) ----
  dotA += __shfl_xor(dotA, 1, 64);
  dotA += __shfl_xor(dotA, 2, 64);
#pragma unroll
  for (int r4 = 0; r4 < 4; ++r4) {
    dotB[r4] += __shfl_xor(dotB[r4], 1, 64);
    dotB[r4] += __shfl_xor(dotB[r4], 2, 64);
  }
  if ((tid & 3) == 0) {
    sub0_l[srow] = dotA;
#pragma unroll
    for (int r4 = 0; r4 < 4; ++r4) sub1_l[srow + 64 * r4] = dotB[r4];
  }
  __syncthreads();  // also drains LDS fragment reads -> eT alias safe

  // ---- v = clip(acc + subs + bias) ----
  const float bv = bias[0];
  const int cc = lane & 15, cr = (lane >> 4) * 4;
  float qmv[4];
#pragma unroll
  for (int n = 0; n < 4; ++n)
    qmv[n] = (float)Qmask[b * 256 + wave * 64 + n * 16 + cc];
  float cmv[4][4];
#pragma unroll
  for (int m = 0; m < 4; ++m)
#pragma unroll
    for (int i = 0; i < 4; ++i)
      cmv[m][i] = (float)Cmask[b * 1024 + m0 + m * 16 + cr + i];

#pragma unroll
  for (int m = 0; m < 4; ++m)
#pragma unroll
    for (int n = 0; n < 4; ++n)
#pragma unroll
      for (int i = 0; i < 4; ++i) {
        float v = acc[m][n][i] + sub0_l[m * 16 + cr + i] +
                  sub1_l[wave * 64 + n * 16 + cc] + bv;
        acc[m][n][i] = fminf(15.f, fmaxf(-15.f, v));
      }

  // ---- column exp into LDS transpose buffer + partial col sums ----
  float ps[4] = {0.f, 0.f, 0.f, 0.f};
#pragma unroll
  for (int m = 0; m < 4; ++m)
#pragma unroll
    for (int n = 0; n < 4; ++n) {
      short4v o;
#pragma unroll
      for (int i = 0; i < 4; ++i) {
        float cm = cmv[m][i];
        float ec = cm * __expf(acc[m][n][i] * cm - 8.f);
        ps[n] += ec;
        o[i] = f2bf(ec);
      }
      *(short4v*)(eT + (wave * 64 + n * 16 + cc) * 72 + m * 16 + cr) = o;
    }
#pragma unroll
  for (int n = 0; n < 4; ++n) {
    ps[n] += __shfl_xor(ps[n], 16, 64);
    ps[n] += __shfl_xor(ps[n], 32, 64);
  }
  if (lane < 16) {
#pragma unroll
    for (int n = 0; n < 4; ++n)
      partial[((size_t)b * 16 + mblk) * 256 + wave * 64 + n * 16 + cc] = ps[n];
  }
  __syncthreads();  // eT complete

  // ---- write Eu [lq][lc] (transposed) ----
  short* Eub = Eu + (size_t)b * 262144 + m0;
#pragma unroll
  for (int it = 0; it < 8; ++it) {
    int q = it * 32 + wave * 8 + (lane >> 3);
    int k = lane & 7;
    short8 v = *(const short8*)(eT + q * 72 + k * 8);
    *(short8*)(Eub + (size_t)q * 1024 + k * 8) = v;
  }

  // ---- row exp + row sum -> S1 = eq/(sum+1e-6) ----
  float rs[4][4];
#pragma unroll
  for (int m = 0; m < 4; ++m)
#pragma unroll
    for (int i = 0; i < 4; ++i) {
      rs[m][i] = 0.f;
#pragma unroll
      for (int n = 0; n < 4; ++n) {
        float eq = qmv[n] * __expf(acc[m][n][i] * qmv[n] - 8.f);
        acc[m][n][i] = eq;
        rs[m][i] += eq;
      }
    }
#pragma unroll
  for (int m = 0; m < 4; ++m)
#pragma unroll
    for (int i = 0; i < 4; ++i) {
      rs[m][i] += __shfl_xor(rs[m][i], 1, 64);
      rs[m][i] += __shfl_xor(rs[m][i], 2, 64);
      rs[m][i] += __shfl_xor(rs[m][i], 4, 64);
      rs[m][i] += __shfl_xor(rs[m][i], 8, 64);
    }
  if (cc == 0) {
#pragma unroll
    for (int m = 0; m < 4; ++m)
#pragma unroll
      for (int i = 0; i < 4; ++i) redS[wave][m * 16 + cr + i] = rs[m][i];
  }
  __syncthreads();

  short* S1b = S1 + (size_t)b * 262144 + (size_t)m0 * 256;
#pragma unroll
  for (int m = 0; m < 4; ++m)
#pragma unroll
    for (int i = 0; i < 4; ++i) {
      int r = m * 16 + cr + i;
      float sum = redS[0][r] + redS[1][r] + redS[2][r] + redS[3][r];
      float inv = 1.f / (sum + 1e-6f);
#pragma unroll
      for (int n = 0; n < 4; ++n)
        S1b[(size_t)r * 256 + wave * 64 + n * 16 + cc] =
            f2bf(acc[m][n][i] * inv);
    }
}

// ---------------- stage1: S_fused || C-transpose || Q-transpose ------------
// flat grid: [0,256) S_fused; [256,2304) prepC; [2304,2816) prepQ

__global__ __launch_bounds__(256) void stage1(
    const float* __restrict__ C, const float* __restrict__ Q,
    const int* __restrict__ Qmask, const int* __restrict__ Cmask,
    const float* __restrict__ w4C, const float* __restrict__ w4Q,
    const float* __restrict__ w4mlu, const float* __restrict__ bias,
    short* __restrict__ S1, short* __restrict__ Eu,
    float* __restrict__ partial, short* __restrict__ Ctb,
    short* __restrict__ QT) {
  __shared__ __attribute__((aligned(16))) char sm[39168];
  const int id = blockIdx.x;
  if (id < 256) {
    s_fused_body(C, Q, Qmask, Cmask, w4C, w4Q, w4mlu, bias, S1, Eu, partial,
                 id >> 4, id & 15, sm);
  } else if (id < 2304) {
    const int p = id - 256, b = p >> 7, t = p & 127;
    prep_tile64(C + (size_t)b * 1024 * 512, Ctb + (size_t)b * 512 * 1024, 1024,
                (t >> 3) * 64, (t & 7) * 64, (short*)sm);
  } else {
    const int p = id - 2304, b = p >> 5, t = p & 31;
    prep_tile64(Q + (size_t)b * 256 * 512, QT + (size_t)b * 1024 * 256, 256,
                (t >> 3) * 64, (t & 7) * 64, (short*)sm);
  }
}

// ---------------- stage2: AB-top || T2 -------------------------------------
// flat grid: [0,512) AB-top (128x128, n0<512); [512,1024) T2 (64x64)

__global__ __launch_bounds__(256) void stage2(
    const short* __restrict__ Ctb, const short* __restrict__ Eu,
    const float* __restrict__ partial, short* __restrict__ QT,
    const short* __restrict__ S1, const float* __restrict__ C,
    float* __restrict__ out) {
  __shared__ __attribute__((aligned(16))) char sm[16384];
  short* ldsA = (short*)sm;
  short* ldsB = (short*)(sm + 8192);
  const int id = blockIdx.x;
  const int lane = threadIdx.x & 63, wave = threadIdx.x >> 6;
  const int cr = (lane >> 4) * 4, cc = lane & 15;

  if (id < 512) {
    // ---- AB-top: out segs {C, A, C*A}, M=1024 N=512(Q^T rows) K=256 ----
    const int b = id >> 5, r = id & 31;
    const int m0 = (r >> 2) * 128, n0 = (r & 3) * 128;
    const int wr = (wave >> 1) * 64, wc = (wave & 1) * 64;
    f32x4 acc[4][4];
    {
      f32x4 z = {0.f, 0.f, 0.f, 0.f};
#pragma unroll
      for (int m = 0; m < 4; ++m)
#pragma unroll
        for (int n = 0; n < 4; ++n) acc[m][n] = z;
    }
    gemm_core(S1 + (size_t)b * 1024 * 256, QT + (size_t)b * 1024 * 256, 256,
              256, 256, m0, n0, ldsA, ldsB, acc);
#pragma unroll
    for (int m = 0; m < 4; ++m)
#pragma unroll
      for (int n = 0; n < 4; ++n)
#pragma unroll
        for (int i = 0; i < 4; ++i) {
          int rr = m0 + wr + m * 16 + cr + i;
          int c = n0 + wc + n * 16 + cc;
          float a = acc[m][n][i];
          float cv = C[((size_t)b * 1024 + rr) * 512 + c];
          size_t base = ((size_t)b * 1024 + rr) * 2048;
          __builtin_nontemporal_store(cv, &out[base + c]);
          __builtin_nontemporal_store(a, &out[base + 512 + c]);
          __builtin_nontemporal_store(cv * a, &out[base + 1024 + c]);
        }
  } else {
    // ---- T2: T^T = Ctb . Eu^T, col-scaled; M=512 N=256 K=1024, 64x64 ----
    const int t = id - 512, b = t >> 5, r = t & 31;
    const int m0 = (r >> 2) * 64, n0 = (r & 3) * 64;
    const int wr = (wave >> 1) * 32, wc = (wave & 1) * 32;
    f32x4 acc[2][2];
    {
      f32x4 z = {0.f, 0.f, 0.f, 0.f};
#pragma unroll
      for (int m = 0; m < 2; ++m)
#pragma unroll
        for (int n = 0; n < 2; ++n) acc[m][n] = z;
    }
    gemm_core64(Ctb + (size_t)b * 512 * 1024, Eu + (size_t)b * 256 * 1024,
                1024, 1024, 1024, m0, n0, ldsA, ldsB, acc);
    const float* pb = partial + (size_t)b * 16 * 256;
    float invv[2];
#pragma unroll
    for (int n = 0; n < 2; ++n) {
      int c = n0 + wc + n * 16 + cc;
      float s = 0.f;
#pragma unroll
      for (int k = 0; k < 16; ++k) s += pb[k * 256 + c];
      invv[n] = 1.f / (s + 1e-6f);
    }
    short* Tp = QT + (size_t)b * 1024 * 256 + 512 * 256;
#pragma unroll
    for (int m = 0; m < 2; ++m)
#pragma unroll
      for (int n = 0; n < 2; ++n)
#pragma unroll
        for (int i = 0; i < 4; ++i) {
          int rr = m0 + wr + m * 16 + cr + i;
          int c = n0 + wc + n * 16 + cc;
          Tp[(size_t)rr * 256 + c] = f2bf(acc[m][n][i] * invv[n]);
        }
  }
}

// ---------------- stage3: AB-bottom (C*Bt segment) -------------------------
// M=1024, N=512 (QT rows 512..1023 = T^T), K=256. grid (8,4,16).

__global__ __launch_bounds__(256) void gemm_ABbot(const short* __restrict__ S1,
                                                  const short* __restrict__ QT,
                                                  const float* __restrict__ C,
                                                  float* __restrict__ out) {
  __shared__ __attribute__((aligned(16))) short ldsA[128 * 32];
  __shared__ __attribute__((aligned(16))) short ldsB[128 * 32];
  const int b = blockIdx.z;
  const int m0 = blockIdx.x * 128, n0 = 512 + blockIdx.y * 128;
  f32x4 acc[4][4];
  {
    f32x4 z = {0.f, 0.f, 0.f, 0.f};
#pragma unroll
    for (int m = 0; m < 4; ++m)
#pragma unroll
      for (int n = 0; n < 4; ++n) acc[m][n] = z;
  }
  const int lane = threadIdx.x & 63, wave = threadIdx.x >> 6;
  const int wr = (wave >> 1) * 64, wc = (wave & 1) * 64;
  const int cr = (lane >> 4) * 4, cc = lane & 15;
  gemm_core(S1 + (size_t)b * 1024 * 256, QT + (size_t)b * 1024 * 256, 256, 256,
            256, m0, n0, ldsA, ldsB, acc);
#pragma unroll
  for (int m = 0; m < 4; ++m)
#pragma unroll
    for (int n = 0; n < 4; ++n)
#pragma unroll
      for (int i = 0; i < 4; ++i) {
        int rr = m0 + wr + m * 16 + cr + i;
        int cq = (n0 - 512) + wc + n * 16 + cc;
        float cv = C[((size_t)b * 1024 + rr) * 512 + cq];
        size_t base = ((size_t)b * 1024 + rr) * 2048;
        __builtin_nontemporal_store(cv * acc[m][n][i], &out[base + 1536 + cq]);
      }
}

// ---------------------------------------------------------------------------

extern "C" void kernel_launch(void* const* d_in, const int* in_sizes, int n_in,
                              void* d_out, int out_size, void* d_ws,
                              size_t ws_size, hipStream_t stream) {
  const float* C = (const float*)d_in[0];
  const float* Q = (const float*)d_in[1];
  const int* Cmask = (const int*)d_in[2];
  const int* Qmask = (const int*)d_in[3];
  const float* w4C = (const float*)d_in[4];
  const float* w4Q = (const float*)d_in[5];
  const float* w4mlu = (const float*)d_in[6];
  const float* bias = (const float*)d_in[7];
  float* out = (float*)d_out;

  size_t off = 0;
  auto alloc = [&](size_t n) {
    void* p = (char*)d_ws + off;
    off += (n + 255) & ~(size_t)255;
    return p;
  };
  short* Ctb = (short*)alloc((size_t)16 * 512 * 1024 * 2);    // [b][d][lc]
  short* QT = (short*)alloc((size_t)16 * 1024 * 256 * 2);     // [b][Q^T;T^T][lq]
  short* S1 = (short*)alloc((size_t)16 * 1024 * 256 * 2);     // [b][lc][lq]
  short* Eu = (short*)alloc((size_t)16 * 256 * 1024 * 2);     // [b][lq][lc]
  float* partial = (float*)alloc((size_t)16 * 16 * 256 * 4);  // [b][mblk][lq]

  stage1<<<dim3(2816), dim3(256), 0, stream>>>(C, Q, Qmask, Cmask, w4C, w4Q,
                                               w4mlu, bias, S1, Eu, partial,
                                               Ctb, QT);
  stage2<<<dim3(1024), dim3(256), 0, stream>>>(Ctb, Eu, partial, QT, S1, C,
                                               out);
  gemm_ABbot<<<dim3(8, 4, 16), dim3(256), 0, stream>>>(S1, QT, C, out);
}